// Round 1
// baseline (309.811 us; speedup 1.0000x reference)
//
#include <hip/hip_runtime.h>
#include <stdint.h>
#include <math.h>

typedef __attribute__((ext_vector_type(8))) short short8;   // 8 bf16 (4 VGPRs)
typedef __attribute__((ext_vector_type(4))) float f32x4;    // 4 fp32 acc

static __device__ __forceinline__ uint16_t f2bf(float f) {
  union { float f; uint32_t u; } v; v.f = f;
  uint32_t r = (v.u + 0x7FFFu + ((v.u >> 16) & 1u)) >> 16;  // RNE
  return (uint16_t)r;
}

static __device__ __forceinline__ float waveReduceSum(float x) {
#pragma unroll
  for (int m = 32; m > 0; m >>= 1) x += __shfl_xor(x, m, 64);
  return x;
}

// ---------------- b_i = ||n_i||^2 : one wave per row (256 f32 = 64 lanes x float4)
__global__ __launch_bounds__(256) void k_noise_b(const float* __restrict__ N,
                                                 float* __restrict__ b) {
  const int wave = threadIdx.x >> 6, lane = threadIdx.x & 63;
  const int i = blockIdx.x * 4 + wave;
  const float4 v = *reinterpret_cast<const float4*>(N + (size_t)i * 256 + lane * 4);
  float s = v.x * v.x + v.y * v.y + v.z * v.z + v.w * v.w;
  s = waveReduceSum(s);
  if (lane == 0) b[i] = s;
}

// ---------------- streaming X pass: a_i = ||x_i||^2, sx = X^T 1, c = X^T b
// grid = (D1/1024) colblocks x (B/64) rowblocks. Wave w owns a 256-col slice.
__global__ __launch_bounds__(256) void k_x_pass(const float* __restrict__ X,
                                                const float* __restrict__ b,
                                                float* __restrict__ a,
                                                float* __restrict__ sx,
                                                float* __restrict__ cx, int D1) {
  const int ncb = D1 >> 10;
  const int colblk = blockIdx.x % ncb;
  const int rowblk = blockIdx.x / ncb;
  const int wave = threadIdx.x >> 6, lane = threadIdx.x & 63;
  const int col = (colblk << 10) + (wave << 8) + (lane << 2);
  const int row0 = rowblk << 6;  // 64 rows per block
  float s0 = 0.f, s1 = 0.f, s2 = 0.f, s3 = 0.f;
  float c0 = 0.f, c1 = 0.f, c2 = 0.f, c3 = 0.f;
  const float* p = X + (size_t)row0 * D1 + col;
  for (int r = 0; r < 64; ++r) {
    const int i = row0 + r;
    const float4 v = *reinterpret_cast<const float4*>(p);
    p += D1;
    const float bi = b[i];
    s0 += v.x; s1 += v.y; s2 += v.z; s3 += v.w;
    c0 += bi * v.x; c1 += bi * v.y; c2 += bi * v.z; c3 += bi * v.w;
    float asq = v.x * v.x + v.y * v.y + v.z * v.z + v.w * v.w;
    asq = waveReduceSum(asq);
    if (lane == 0) atomicAdd(&a[i], asq);
  }
  atomicAdd(&sx[col + 0], s0); atomicAdd(&sx[col + 1], s1);
  atomicAdd(&sx[col + 2], s2); atomicAdd(&sx[col + 3], s3);
  atomicAdd(&cx[col + 0], c0); atomicAdd(&cx[col + 1], c1);
  atomicAdd(&cx[col + 2], c2); atomicAdd(&cx[col + 3], c3);
}

// ---------------- sn = N^T 1, an = N^T a : thread t owns column t
__global__ __launch_bounds__(256) void k_noise2(const float* __restrict__ N,
                                                const float* __restrict__ a,
                                                float* __restrict__ sn,
                                                float* __restrict__ an) {
  const int t = threadIdx.x;
  const int i0 = blockIdx.x << 6;
  float ssn = 0.f, san = 0.f;
  for (int r = 0; r < 64; ++r) {
    const int i = i0 + r;
    const float v = N[(size_t)i * 256 + t];
    ssn += v;
    san += a[i] * v;
  }
  atomicAdd(&sn[t], ssn);
  atomicAdd(&an[t], san);
}

// ---------------- F = ||X^T N||_F^2 via bf16 MFMA, M never materialized.
// Block: 64 p-rows x all 256 l-cols, full K=B. LDS tiles [p][i] / [l][i],
// stride 40 bf16 (pad: conflict-free b128 frag reads). acc layout irrelevant
// for F (sum of squares over whole tile).
__global__ __launch_bounds__(256) void k_gemm_f(const float* __restrict__ X,
                                                const float* __restrict__ Nz,
                                                float* __restrict__ Fout,
                                                int B, int D1) {
  __shared__ uint16_t Abf[64 * 40];
  __shared__ uint16_t Bbf[256 * 40];
  __shared__ float red[4];
  const int tid = threadIdx.x;
  const int pbase = blockIdx.x << 6;
  const int wave = tid >> 6, lane = tid & 63;
  const int lr = lane & 15, lh = lane >> 4;

  f32x4 acc[4][4];
#pragma unroll
  for (int i = 0; i < 4; ++i)
#pragma unroll
    for (int j = 0; j < 4; ++j) acc[i][j] = (f32x4){0.f, 0.f, 0.f, 0.f};

  // staging task coords (ig in low bits -> LDS write conflicts spread to ~4-way,
  // 8-lane/128B coalesced global segments)
  const int igx = tid & 7, p4x = ((tid >> 3) & 15) << 2;        // X: tid<128
  const int ign0 = tid & 7, l4n0 = (tid >> 3) << 2;             // N task 0
  const int ign1 = (tid + 256) & 7, l4n1 = ((tid + 256) >> 3) << 2;  // N task 1

  float4 xr0, xr1, xr2, xr3;
  float4 n0r0, n0r1, n0r2, n0r3;
  float4 n1r0, n1r1, n1r2, n1r3;

  auto load_stage = [&](int i0) {
    if (tid < 128) {
      const float* src = X + (size_t)(i0 + igx * 4) * D1 + pbase + p4x;
      xr0 = *reinterpret_cast<const float4*>(src);
      xr1 = *reinterpret_cast<const float4*>(src + D1);
      xr2 = *reinterpret_cast<const float4*>(src + 2 * (size_t)D1);
      xr3 = *reinterpret_cast<const float4*>(src + 3 * (size_t)D1);
    }
    {
      const float* src = Nz + (size_t)(i0 + ign0 * 4) * 256 + l4n0;
      n0r0 = *reinterpret_cast<const float4*>(src);
      n0r1 = *reinterpret_cast<const float4*>(src + 256);
      n0r2 = *reinterpret_cast<const float4*>(src + 512);
      n0r3 = *reinterpret_cast<const float4*>(src + 768);
    }
    {
      const float* src = Nz + (size_t)(i0 + ign1 * 4) * 256 + l4n1;
      n1r0 = *reinterpret_cast<const float4*>(src);
      n1r1 = *reinterpret_cast<const float4*>(src + 256);
      n1r2 = *reinterpret_cast<const float4*>(src + 512);
      n1r3 = *reinterpret_cast<const float4*>(src + 768);
    }
  };

  auto store_stage = [&]() {
    ushort4 w;
    if (tid < 128) {
      w.x = f2bf(xr0.x); w.y = f2bf(xr1.x); w.z = f2bf(xr2.x); w.w = f2bf(xr3.x);
      *reinterpret_cast<ushort4*>(&Abf[(p4x + 0) * 40 + igx * 4]) = w;
      w.x = f2bf(xr0.y); w.y = f2bf(xr1.y); w.z = f2bf(xr2.y); w.w = f2bf(xr3.y);
      *reinterpret_cast<ushort4*>(&Abf[(p4x + 1) * 40 + igx * 4]) = w;
      w.x = f2bf(xr0.z); w.y = f2bf(xr1.z); w.z = f2bf(xr2.z); w.w = f2bf(xr3.z);
      *reinterpret_cast<ushort4*>(&Abf[(p4x + 2) * 40 + igx * 4]) = w;
      w.x = f2bf(xr0.w); w.y = f2bf(xr1.w); w.z = f2bf(xr2.w); w.w = f2bf(xr3.w);
      *reinterpret_cast<ushort4*>(&Abf[(p4x + 3) * 40 + igx * 4]) = w;
    }
    w.x = f2bf(n0r0.x); w.y = f2bf(n0r1.x); w.z = f2bf(n0r2.x); w.w = f2bf(n0r3.x);
    *reinterpret_cast<ushort4*>(&Bbf[(l4n0 + 0) * 40 + ign0 * 4]) = w;
    w.x = f2bf(n0r0.y); w.y = f2bf(n0r1.y); w.z = f2bf(n0r2.y); w.w = f2bf(n0r3.y);
    *reinterpret_cast<ushort4*>(&Bbf[(l4n0 + 1) * 40 + ign0 * 4]) = w;
    w.x = f2bf(n0r0.z); w.y = f2bf(n0r1.z); w.z = f2bf(n0r2.z); w.w = f2bf(n0r3.z);
    *reinterpret_cast<ushort4*>(&Bbf[(l4n0 + 2) * 40 + ign0 * 4]) = w;
    w.x = f2bf(n0r0.w); w.y = f2bf(n0r1.w); w.z = f2bf(n0r2.w); w.w = f2bf(n0r3.w);
    *reinterpret_cast<ushort4*>(&Bbf[(l4n0 + 3) * 40 + ign0 * 4]) = w;

    w.x = f2bf(n1r0.x); w.y = f2bf(n1r1.x); w.z = f2bf(n1r2.x); w.w = f2bf(n1r3.x);
    *reinterpret_cast<ushort4*>(&Bbf[(l4n1 + 0) * 40 + ign1 * 4]) = w;
    w.x = f2bf(n1r0.y); w.y = f2bf(n1r1.y); w.z = f2bf(n1r2.y); w.w = f2bf(n1r3.y);
    *reinterpret_cast<ushort4*>(&Bbf[(l4n1 + 1) * 40 + ign1 * 4]) = w;
    w.x = f2bf(n1r0.z); w.y = f2bf(n1r1.z); w.z = f2bf(n1r2.z); w.w = f2bf(n1r3.z);
    *reinterpret_cast<ushort4*>(&Bbf[(l4n1 + 2) * 40 + ign1 * 4]) = w;
    w.x = f2bf(n1r0.w); w.y = f2bf(n1r1.w); w.z = f2bf(n1r2.w); w.w = f2bf(n1r3.w);
    *reinterpret_cast<ushort4*>(&Bbf[(l4n1 + 3) * 40 + ign1 * 4]) = w;
  };

  load_stage(0);
  for (int i0 = 0; i0 < B; i0 += 32) {
    store_stage();
    __syncthreads();
    if (i0 + 32 < B) load_stage(i0 + 32);  // prefetch overlaps MFMA below

    short8 af[4], bfv[4];
#pragma unroll
    for (int ps = 0; ps < 4; ++ps)
      af[ps] = *reinterpret_cast<const short8*>(&Abf[(ps * 16 + lr) * 40 + lh * 8]);
#pragma unroll
    for (int q = 0; q < 4; ++q)
      bfv[q] = *reinterpret_cast<const short8*>(&Bbf[((wave * 4 + q) * 16 + lr) * 40 + lh * 8]);
#pragma unroll
    for (int ps = 0; ps < 4; ++ps)
#pragma unroll
      for (int q = 0; q < 4; ++q)
        acc[ps][q] = __builtin_amdgcn_mfma_f32_16x16x32_bf16(af[ps], bfv[q], acc[ps][q], 0, 0, 0);
    __syncthreads();
  }

  float loc = 0.f;
#pragma unroll
  for (int ps = 0; ps < 4; ++ps)
#pragma unroll
    for (int q = 0; q < 4; ++q)
#pragma unroll
      for (int e = 0; e < 4; ++e) loc += acc[ps][q][e] * acc[ps][q][e];
  loc = waveReduceSum(loc);
  if (lane == 0) red[wave] = loc;
  __syncthreads();
  if (tid == 0) atomicAdd(Fout, red[0] + red[1] + red[2] + red[3]);
}

// ---------------- final combine (double precision scalar math)
__global__ __launch_bounds__(256) void k_final(const float* __restrict__ a,
                                               const float* __restrict__ b,
                                               const float* __restrict__ sx,
                                               const float* __restrict__ cx,
                                               const float* __restrict__ sn,
                                               const float* __restrict__ an,
                                               const float* __restrict__ Fp,
                                               float* __restrict__ out, int B, int D1) {
  const int tid = threadIdx.x;
  float sa = 0.f, sb = 0.f, sab = 0.f, t2 = 0.f;
  for (int i = tid; i < B; i += 256) {
    const float ai = a[i], bi = b[i];
    sa += ai; sb += bi; sab += ai * bi;
  }
  float t1 = an[tid] * sn[tid];  // D2 == 256 == blockDim
  for (int k = tid; k < D1; k += 256) t2 += cx[k] * sx[k];

  sa = waveReduceSum(sa); sb = waveReduceSum(sb); sab = waveReduceSum(sab);
  t1 = waveReduceSum(t1); t2 = waveReduceSum(t2);
  __shared__ float R[5][4];
  const int wave = tid >> 6, lane = tid & 63;
  if (lane == 0) { R[0][wave] = sa; R[1][wave] = sb; R[2][wave] = sab; R[3][wave] = t1; R[4][wave] = t2; }
  __syncthreads();
  if (tid == 0) {
    double Sa = 0, Sb = 0, Sab = 0, T1 = 0, T2 = 0;
    for (int w = 0; w < 4; ++w) {
      Sa += R[0][w]; Sb += R[1][w]; Sab += R[2][w]; T1 += R[3][w]; T2 += R[4][w];
    }
    const double F = (double)Fp[0];
    const double total = 2.0 * (double)B * Sab + 2.0 * Sa * Sb - 4.0 * T1 - 4.0 * T2 + 4.0 * F;
    const double denom = (double)D1 * 256.0 * (double)B * (double)B;
    out[0] = (float)exp(-total / denom);
  }
}

extern "C" void kernel_launch(void* const* d_in, const int* in_sizes, int n_in,
                              void* d_out, int out_size, void* d_ws, size_t ws_size,
                              hipStream_t stream) {
  const float* noises = (const float*)d_in[0];   // [B, 256]
  const float* images = (const float*)d_in[1];   // [B, D1]
  const int B = in_sizes[0] / 256;               // 4096
  const int D1 = in_sizes[1] / B;                // 12288

  float* ws = (float*)d_ws;
  float* a  = ws;                       // B
  float* b  = ws + B;                   // B
  float* sx = ws + 2 * B;               // D1
  float* cx = ws + 2 * B + D1;          // D1
  float* sn = ws + 2 * B + 2 * D1;        // 256
  float* an = ws + 2 * B + 2 * D1 + 256;  // 256
  float* Fp = ws + 2 * B + 2 * D1 + 512;  // 1
  float* outf = (float*)d_out;

  hipMemsetAsync(d_ws, 0, (size_t)(2 * B + 2 * D1 + 513) * sizeof(float), stream);
  k_noise_b<<<B / 4, 256, 0, stream>>>(noises, b);
  k_x_pass<<<(D1 / 1024) * (B / 64), 256, 0, stream>>>(images, b, a, sx, cx, D1);
  k_noise2<<<B / 64, 256, 0, stream>>>(noises, a, sn, an);
  k_gemm_f<<<D1 / 64, 256, 0, stream>>>(images, noises, Fp, B, D1);
  k_final<<<1, 256, 0, stream>>>(a, b, sx, cx, sn, an, Fp, outf, B, D1);
}

// Round 2
// 177.673 us; speedup vs baseline: 1.7437x; 1.7437x over previous
//
#include <hip/hip_runtime.h>
#include <stdint.h>
#include <math.h>

typedef __attribute__((ext_vector_type(8))) short short8;   // 8 bf16 (4 VGPRs)
typedef __attribute__((ext_vector_type(4))) float f32x4;    // 4 fp32 acc

typedef __attribute__((address_space(1))) const uint32_t g_u32;
typedef __attribute__((address_space(3))) uint32_t l_u32;

static __device__ __forceinline__ uint16_t f2bf(float f) {
  union { float f; uint32_t u; } v; v.f = f;
  uint32_t r = (v.u + 0x7FFFu + ((v.u >> 16) & 1u)) >> 16;  // RNE
  return (uint16_t)r;
}

static __device__ __forceinline__ float waveReduceSum(float x) {
#pragma unroll
  for (int m = 32; m > 0; m >>= 1) x += __shfl_xor(x, m, 64);
  return x;
}

// ---------------- b_i = ||n_i||^2 : one wave per row
__global__ __launch_bounds__(256) void k_noise_b(const float* __restrict__ N,
                                                 float* __restrict__ b) {
  const int wave = threadIdx.x >> 6, lane = threadIdx.x & 63;
  const int i = blockIdx.x * 4 + wave;
  const float4 v = *reinterpret_cast<const float4*>(N + (size_t)i * 256 + lane * 4);
  float s = v.x * v.x + v.y * v.y + v.z * v.z + v.w * v.w;
  s = waveReduceSum(s);
  if (lane == 0) b[i] = s;
}

// ---------------- N^T bf16, pre-swizzled per 32-k tile so a LINEAR 16KB copy
// (global_load_lds) yields the swizzled LDS layout:
//   tile byte(l, k') = l*64 + ((k'>>3) ^ (l&3))*16 + (k'&7)*2,  k' in [0,32)
__global__ __launch_bounds__(256) void k_nt(const float* __restrict__ N,
                                            uint16_t* __restrict__ Nt) {
  __shared__ __align__(16) uint16_t T[256 * 72];  // [l][k] k=0..63, pad 72
  const int i0 = blockIdx.x * 64;
  const int tid = threadIdx.x;
#pragma unroll
  for (int it = 0; it < 16; ++it) {
    const int k = (tid >> 6) + it * 4;
    const int l4 = (tid & 63) * 4;
    const float4 v = *reinterpret_cast<const float4*>(N + (size_t)(i0 + k) * 256 + l4);
    T[(l4 + 0) * 72 + k] = f2bf(v.x);
    T[(l4 + 1) * 72 + k] = f2bf(v.y);
    T[(l4 + 2) * 72 + k] = f2bf(v.z);
    T[(l4 + 3) * 72 + k] = f2bf(v.w);
  }
  __syncthreads();
  const int l = tid;
#pragma unroll
  for (int tt = 0; tt < 2; ++tt) {
    const int tg = blockIdx.x * 2 + tt;  // global kstep (32-row tile) index
#pragma unroll
    for (int c = 0; c < 4; ++c) {
      const short8 v = *reinterpret_cast<const short8*>(&T[l * 72 + tt * 32 + c * 8]);
      *reinterpret_cast<short8*>((char*)Nt + (size_t)tg * 16384 + l * 64 +
                                 ((c ^ (l & 3)) << 4)) = v;
    }
  }
}

// ---------------- streaming X pass: a_i, sx = X^T 1, cx = X^T b (8-row batched reduce)
__global__ __launch_bounds__(256) void k_x_pass(const float* __restrict__ X,
                                                const float* __restrict__ b,
                                                float* __restrict__ a,
                                                float* __restrict__ sx,
                                                float* __restrict__ cx, int D1) {
  const int ncb = D1 >> 10;
  const int colblk = blockIdx.x % ncb;
  const int rowblk = blockIdx.x / ncb;
  const int wv = threadIdx.x >> 6, lane = threadIdx.x & 63;
  const int col = (colblk << 10) + (wv << 8) + (lane << 2);
  const int row0 = rowblk << 6;
  float s0 = 0.f, s1 = 0.f, s2 = 0.f, s3 = 0.f;
  float c0 = 0.f, c1 = 0.f, c2 = 0.f, c3 = 0.f;
  const float* p = X + (size_t)row0 * D1 + col;
  for (int r8 = 0; r8 < 64; r8 += 8) {
    float asq[8];
#pragma unroll
    for (int r = 0; r < 8; ++r) {
      const float4 v = *reinterpret_cast<const float4*>(p + (size_t)(r8 + r) * D1);
      const float bi = b[row0 + r8 + r];
      s0 += v.x; s1 += v.y; s2 += v.z; s3 += v.w;
      c0 += bi * v.x; c1 += bi * v.y; c2 += bi * v.z; c3 += bi * v.w;
      asq[r] = v.x * v.x + v.y * v.y + v.z * v.z + v.w * v.w;
    }
#pragma unroll
    for (int m = 1; m < 64; m <<= 1) {
#pragma unroll
      for (int r = 0; r < 8; ++r) asq[r] += __shfl_xor(asq[r], m, 64);
    }
    float myv = asq[0];
#pragma unroll
    for (int r = 1; r < 8; ++r) myv = (lane == r) ? asq[r] : myv;
    if (lane < 8) atomicAdd(&a[row0 + r8 + lane], myv);
  }
  atomicAdd(&sx[col + 0], s0); atomicAdd(&sx[col + 1], s1);
  atomicAdd(&sx[col + 2], s2); atomicAdd(&sx[col + 3], s3);
  atomicAdd(&cx[col + 0], c0); atomicAdd(&cx[col + 1], c1);
  atomicAdd(&cx[col + 2], c2); atomicAdd(&cx[col + 3], c3);
}

// ---------------- sn = N^T 1, an = N^T a
__global__ __launch_bounds__(256) void k_noise2(const float* __restrict__ N,
                                                const float* __restrict__ a,
                                                float* __restrict__ sn,
                                                float* __restrict__ an) {
  const int t = threadIdx.x;
  const int i0 = blockIdx.x << 6;
  float ssn = 0.f, san = 0.f;
  for (int r = 0; r < 64; ++r) {
    const int i = i0 + r;
    const float v = N[(size_t)i * 256 + t];
    ssn += v;
    san += a[i] * v;
  }
  atomicAdd(&sn[t], ssn);
  atomicAdd(&an[t], san);
}

// ---------------- K-split GEMM: partial M[p][l] += X^T N over this block's K-chunk.
// tile 64p x 256l, 4 k-chunks -> grid (D1/64)*4 = 768, 3 blocks/CU.
// B (N^T) staged via global_load_lds from pre-swizzled Nt; A staged fp32->bf16.
__global__ __launch_bounds__(256, 3) void k_gemm_f2(const float* __restrict__ X,
                                                    const uint16_t* __restrict__ Nt,
                                                    float* __restrict__ M,
                                                    int B, int D1) {
  __shared__ __align__(16) uint16_t NB[2][8192];   // 2 x 16 KB (256l x 32k bf16 swz)
  __shared__ __align__(16) uint16_t AB[2][64 * 40];
  const int tid = threadIdx.x;
  const int w = tid >> 6, lane = tid & 63;
  const int lr = lane & 15, lh = lane >> 4;
  const int nks = B >> 7;                 // ksteps per chunk (32)
  const int pt = blockIdx.x >> 2, kc = blockIdx.x & 3;
  const int pbase = pt << 6;
  const int ks0 = kc * nks;               // starting global kstep

  f32x4 acc[4][4];
#pragma unroll
  for (int i = 0; i < 4; ++i)
#pragma unroll
    for (int j = 0; j < 4; ++j) acc[i][j] = (f32x4){0.f, 0.f, 0.f, 0.f};

  // A staging: thread owns col p = tid&63, k-octet k8 = (tid>>6)*8 within 32-row step
  const int ap = tid & 63, ak8 = (tid >> 6) << 3;
  const float* Xbase = X + (size_t)(ks0 * 32 + ak8) * D1 + pbase + ap;
  float xr[8];

#define GLL_B(S, BUF)                                                              \
  {                                                                                \
    const char* gsrc_ = (const char*)Nt + (size_t)(ks0 + (S)) * 16384 +            \
                        ((size_t)w << 10) + (size_t)lane * 16;                     \
    _Pragma("unroll")                                                              \
    for (int j_ = 0; j_ < 4; ++j_) {                                               \
      __builtin_amdgcn_global_load_lds((g_u32*)(gsrc_ + ((size_t)j_ << 12)),       \
                                       (l_u32*)&NB[BUF][(j_ * 4 + w) << 9],        \
                                       16, 0, 0);                                  \
    }                                                                              \
  }
#define A_LOADS(S)                                                                 \
  {                                                                                \
    const float* p_ = Xbase + (size_t)(S) * 32 * D1;                               \
    _Pragma("unroll")                                                              \
    for (int r_ = 0; r_ < 8; ++r_) xr[r_] = p_[(size_t)r_ * D1];                   \
  }

  GLL_B(0, 0);
  A_LOADS(0);

  for (int s = 0; s < nks; ++s) {
    const int buf = s & 1;
    {  // store A (implicit vmcnt wait here drains this iter's gll too)
      union { uint16_t u[8]; short8 v; } pk;
#pragma unroll
      for (int r = 0; r < 8; ++r) pk.u[r] = f2bf(xr[r]);
      *reinterpret_cast<short8*>(&AB[buf][ap * 40 + ak8]) = pk.v;
    }
    __syncthreads();
    if (s + 1 < nks) {  // prefetch overlaps frag reads + MFMA below
      GLL_B(s + 1, buf ^ 1);
      A_LOADS(s + 1);
    }
    short8 af[4], bfv[4];
#pragma unroll
    for (int ps = 0; ps < 4; ++ps)
      af[ps] = *reinterpret_cast<const short8*>(&AB[buf][(ps * 16 + lr) * 40 + lh * 8]);
#pragma unroll
    for (int q = 0; q < 4; ++q) {
      const int l = (w << 6) + (q << 4) + lr;
      bfv[q] = *reinterpret_cast<const short8*>(&NB[buf][l * 32 + ((lh ^ (l & 3)) << 3)]);
    }
#pragma unroll
    for (int ps = 0; ps < 4; ++ps)
#pragma unroll
      for (int q = 0; q < 4; ++q)
        acc[ps][q] = __builtin_amdgcn_mfma_f32_16x16x32_bf16(af[ps], bfv[q], acc[ps][q], 0, 0, 0);
    __syncthreads();
  }
#undef GLL_B
#undef A_LOADS

  // epilogue: C/D layout col=lane&15 (l), row=(lane>>4)*4+e (p)  [m89-verified]
#pragma unroll
  for (int ps = 0; ps < 4; ++ps)
#pragma unroll
    for (int q = 0; q < 4; ++q)
#pragma unroll
      for (int e = 0; e < 4; ++e) {
        const int p = pbase + ps * 16 + lh * 4 + e;
        const int l = (w << 6) + (q << 4) + lr;
        atomicAdd(&M[(size_t)p * 256 + l], acc[ps][q][e]);
      }
}

// ---------------- F = sum(M^2)
__global__ __launch_bounds__(256) void k_square(const float* __restrict__ M,
                                                float* __restrict__ Fp, int nf4) {
  __shared__ float red[4];
  float s = 0.f;
  for (int idx = blockIdx.x * 256 + threadIdx.x; idx < nf4; idx += gridDim.x * 256) {
    const float4 v = reinterpret_cast<const float4*>(M)[idx];
    s += v.x * v.x + v.y * v.y + v.z * v.z + v.w * v.w;
  }
  s = waveReduceSum(s);
  const int wave = threadIdx.x >> 6, lane = threadIdx.x & 63;
  if (lane == 0) red[wave] = s;
  __syncthreads();
  if (threadIdx.x == 0) atomicAdd(Fp, red[0] + red[1] + red[2] + red[3]);
}

// ---------------- round-1 fallback GEMM (no workspace M needed)
__global__ __launch_bounds__(256) void k_gemm_f(const float* __restrict__ X,
                                                const float* __restrict__ Nz,
                                                float* __restrict__ Fout,
                                                int B, int D1) {
  __shared__ uint16_t Abf[64 * 40];
  __shared__ uint16_t Bbf[256 * 40];
  __shared__ float red[4];
  const int tid = threadIdx.x;
  const int pbase = blockIdx.x << 6;
  const int wave = tid >> 6, lane = tid & 63;
  const int lr = lane & 15, lh = lane >> 4;

  f32x4 acc[4][4];
#pragma unroll
  for (int i = 0; i < 4; ++i)
#pragma unroll
    for (int j = 0; j < 4; ++j) acc[i][j] = (f32x4){0.f, 0.f, 0.f, 0.f};

  const int igx = tid & 7, p4x = ((tid >> 3) & 15) << 2;
  const int ign0 = tid & 7, l4n0 = (tid >> 3) << 2;
  const int ign1 = (tid + 256) & 7, l4n1 = ((tid + 256) >> 3) << 2;

  float4 xr0, xr1, xr2, xr3;
  float4 n0r0, n0r1, n0r2, n0r3;
  float4 n1r0, n1r1, n1r2, n1r3;

  auto load_stage = [&](int i0) {
    if (tid < 128) {
      const float* src = X + (size_t)(i0 + igx * 4) * D1 + pbase + p4x;
      xr0 = *reinterpret_cast<const float4*>(src);
      xr1 = *reinterpret_cast<const float4*>(src + D1);
      xr2 = *reinterpret_cast<const float4*>(src + 2 * (size_t)D1);
      xr3 = *reinterpret_cast<const float4*>(src + 3 * (size_t)D1);
    }
    {
      const float* src = Nz + (size_t)(i0 + ign0 * 4) * 256 + l4n0;
      n0r0 = *reinterpret_cast<const float4*>(src);
      n0r1 = *reinterpret_cast<const float4*>(src + 256);
      n0r2 = *reinterpret_cast<const float4*>(src + 512);
      n0r3 = *reinterpret_cast<const float4*>(src + 768);
    }
    {
      const float* src = Nz + (size_t)(i0 + ign1 * 4) * 256 + l4n1;
      n1r0 = *reinterpret_cast<const float4*>(src);
      n1r1 = *reinterpret_cast<const float4*>(src + 256);
      n1r2 = *reinterpret_cast<const float4*>(src + 512);
      n1r3 = *reinterpret_cast<const float4*>(src + 768);
    }
  };

  auto store_stage = [&]() {
    ushort4 w;
    if (tid < 128) {
      w.x = f2bf(xr0.x); w.y = f2bf(xr1.x); w.z = f2bf(xr2.x); w.w = f2bf(xr3.x);
      *reinterpret_cast<ushort4*>(&Abf[(p4x + 0) * 40 + igx * 4]) = w;
      w.x = f2bf(xr0.y); w.y = f2bf(xr1.y); w.z = f2bf(xr2.y); w.w = f2bf(xr3.y);
      *reinterpret_cast<ushort4*>(&Abf[(p4x + 1) * 40 + igx * 4]) = w;
      w.x = f2bf(xr0.z); w.y = f2bf(xr1.z); w.z = f2bf(xr2.z); w.w = f2bf(xr3.z);
      *reinterpret_cast<ushort4*>(&Abf[(p4x + 2) * 40 + igx * 4]) = w;
      w.x = f2bf(xr0.w); w.y = f2bf(xr1.w); w.z = f2bf(xr2.w); w.w = f2bf(xr3.w);
      *reinterpret_cast<ushort4*>(&Abf[(p4x + 3) * 40 + igx * 4]) = w;
    }
    w.x = f2bf(n0r0.x); w.y = f2bf(n0r1.x); w.z = f2bf(n0r2.x); w.w = f2bf(n0r3.x);
    *reinterpret_cast<ushort4*>(&Bbf[(l4n0 + 0) * 40 + ign0 * 4]) = w;
    w.x = f2bf(n0r0.y); w.y = f2bf(n0r1.y); w.z = f2bf(n0r2.y); w.w = f2bf(n0r3.y);
    *reinterpret_cast<ushort4*>(&Bbf[(l4n0 + 1) * 40 + ign0 * 4]) = w;
    w.x = f2bf(n0r0.z); w.y = f2bf(n0r1.z); w.z = f2bf(n0r2.z); w.w = f2bf(n0r3.z);
    *reinterpret_cast<ushort4*>(&Bbf[(l4n0 + 2) * 40 + ign0 * 4]) = w;
    w.x = f2bf(n0r0.w); w.y = f2bf(n0r1.w); w.z = f2bf(n0r2.w); w.w = f2bf(n0r3.w);
    *reinterpret_cast<ushort4*>(&Bbf[(l4n0 + 3) * 40 + ign0 * 4]) = w;

    w.x = f2bf(n1r0.x); w.y = f2bf(n1r1.x); w.z = f2bf(n1r2.x); w.w = f2bf(n1r3.x);
    *reinterpret_cast<ushort4*>(&Bbf[(l4n1 + 0) * 40 + ign1 * 4]) = w;
    w.x = f2bf(n1r0.y); w.y = f2bf(n1r1.y); w.z = f2bf(n1r2.y); w.w = f2bf(n1r3.y);
    *reinterpret_cast<ushort4*>(&Bbf[(l4n1 + 1) * 40 + ign1 * 4]) = w;
    w.x = f2bf(n1r0.z); w.y = f2bf(n1r1.z); w.z = f2bf(n1r2.z); w.w = f2bf(n1r3.z);
    *reinterpret_cast<ushort4*>(&Bbf[(l4n1 + 2) * 40 + ign1 * 4]) = w;
    w.x = f2bf(n1r0.w); w.y = f2bf(n1r1.w); w.z = f2bf(n1r2.w); w.w = f2bf(n1r3.w);
    *reinterpret_cast<ushort4*>(&Bbf[(l4n1 + 3) * 40 + ign1 * 4]) = w;
  };

  load_stage(0);
  for (int i0 = 0; i0 < B; i0 += 32) {
    store_stage();
    __syncthreads();
    if (i0 + 32 < B) load_stage(i0 + 32);

    short8 af[4], bfv[4];
#pragma unroll
    for (int ps = 0; ps < 4; ++ps)
      af[ps] = *reinterpret_cast<const short8*>(&Abf[(ps * 16 + lr) * 40 + lh * 8]);
#pragma unroll
    for (int q = 0; q < 4; ++q)
      bfv[q] = *reinterpret_cast<const short8*>(&Bbf[((wave * 4 + q) * 16 + lr) * 40 + lh * 8]);
#pragma unroll
    for (int ps = 0; ps < 4; ++ps)
#pragma unroll
      for (int q = 0; q < 4; ++q)
        acc[ps][q] = __builtin_amdgcn_mfma_f32_16x16x32_bf16(af[ps], bfv[q], acc[ps][q], 0, 0, 0);
    __syncthreads();
  }

  float loc = 0.f;
#pragma unroll
  for (int ps = 0; ps < 4; ++ps)
#pragma unroll
    for (int q = 0; q < 4; ++q)
#pragma unroll
      for (int e = 0; e < 4; ++e) loc += acc[ps][q][e] * acc[ps][q][e];
  loc = waveReduceSum(loc);
  if (lane == 0) red[wave] = loc;
  __syncthreads();
  if (tid == 0) atomicAdd(Fout, red[0] + red[1] + red[2] + red[3]);
}

// ---------------- final combine
__global__ __launch_bounds__(256) void k_final(const float* __restrict__ a,
                                               const float* __restrict__ b,
                                               const float* __restrict__ sx,
                                               const float* __restrict__ cx,
                                               const float* __restrict__ sn,
                                               const float* __restrict__ an,
                                               const float* __restrict__ Fp,
                                               float* __restrict__ out, int B, int D1) {
  const int tid = threadIdx.x;
  float sa = 0.f, sb = 0.f, sab = 0.f, t2 = 0.f;
  for (int i = tid; i < B; i += 256) {
    const float ai = a[i], bi = b[i];
    sa += ai; sb += bi; sab += ai * bi;
  }
  float t1 = an[tid] * sn[tid];
  for (int k = tid; k < D1; k += 256) t2 += cx[k] * sx[k];

  sa = waveReduceSum(sa); sb = waveReduceSum(sb); sab = waveReduceSum(sab);
  t1 = waveReduceSum(t1); t2 = waveReduceSum(t2);
  __shared__ float R[5][4];
  const int wave = tid >> 6, lane = tid & 63;
  if (lane == 0) { R[0][wave] = sa; R[1][wave] = sb; R[2][wave] = sab; R[3][wave] = t1; R[4][wave] = t2; }
  __syncthreads();
  if (tid == 0) {
    double Sa = 0, Sb = 0, Sab = 0, T1 = 0, T2 = 0;
    for (int w = 0; w < 4; ++w) {
      Sa += R[0][w]; Sb += R[1][w]; Sab += R[2][w]; T1 += R[3][w]; T2 += R[4][w];
    }
    const double F = (double)Fp[0];
    const double total = 2.0 * (double)B * Sab + 2.0 * Sa * Sb - 4.0 * T1 - 4.0 * T2 + 4.0 * F;
    const double denom = (double)D1 * 256.0 * (double)B * (double)B;
    out[0] = (float)exp(-total / denom);
  }
}

extern "C" void kernel_launch(void* const* d_in, const int* in_sizes, int n_in,
                              void* d_out, int out_size, void* d_ws, size_t ws_size,
                              hipStream_t stream) {
  const float* noises = (const float*)d_in[0];   // [B, 256]
  const float* images = (const float*)d_in[1];   // [B, D1]
  const int B = in_sizes[0] / 256;               // 4096
  const int D1 = in_sizes[1] / B;                // 12288

  float* ws = (float*)d_ws;
  float* a  = ws;                         // B
  float* b  = ws + B;                     // B
  float* sx = ws + 2 * B;                 // D1
  float* cx = ws + 2 * B + D1;            // D1
  float* sn = ws + 2 * B + 2 * D1;        // 256
  float* an = ws + 2 * B + 2 * D1 + 256;  // 256
  float* Fp = ws + 2 * B + 2 * D1 + 512;  // 1
  const size_t m_off = 36864;                       // floats (aligned past scalars)
  float* M  = ws + m_off;                            // D1*256 floats
  uint16_t* Nt = (uint16_t*)(ws + m_off + (size_t)D1 * 256);  // B*256 bf16 swizzled
  float* outf = (float*)d_out;

  const size_t need = (m_off + (size_t)D1 * 256) * sizeof(float) + (size_t)B * 256 * 2;
  const bool big = ws_size >= need;

  if (big) {
    // zero scalars + M in one memset (covers [0, end of M))
    hipMemsetAsync(d_ws, 0, (m_off + (size_t)D1 * 256) * sizeof(float), stream);
    k_noise_b<<<B / 4, 256, 0, stream>>>(noises, b);
    k_nt<<<B / 64, 256, 0, stream>>>(noises, Nt);
    k_x_pass<<<(D1 / 1024) * (B / 64), 256, 0, stream>>>(images, b, a, sx, cx, D1);
    k_noise2<<<B / 64, 256, 0, stream>>>(noises, a, sn, an);
    k_gemm_f2<<<(D1 / 64) * 4, 256, 0, stream>>>(images, Nt, M, B, D1);
    k_square<<<512, 256, 0, stream>>>(M, Fp, D1 * 256 / 4);
    k_final<<<1, 256, 0, stream>>>(a, b, sx, cx, sn, an, Fp, outf, B, D1);
  } else {
    hipMemsetAsync(d_ws, 0, (size_t)(2 * B + 2 * D1 + 513) * sizeof(float), stream);
    k_noise_b<<<B / 4, 256, 0, stream>>>(noises, b);
    k_x_pass<<<(D1 / 1024) * (B / 64), 256, 0, stream>>>(images, b, a, sx, cx, D1);
    k_noise2<<<B / 64, 256, 0, stream>>>(noises, a, sn, an);
    k_gemm_f<<<D1 / 64, 256, 0, stream>>>(images, noises, Fp, B, D1);
    k_final<<<1, 256, 0, stream>>>(a, b, sx, cx, sn, an, Fp, outf, B, D1);
  }
}

// Round 3
// 151.549 us; speedup vs baseline: 2.0443x; 1.1724x over previous
//
#include <hip/hip_runtime.h>
#include <stdint.h>
#include <math.h>

typedef __attribute__((ext_vector_type(8))) short short8;   // 8 bf16 (4 VGPRs)
typedef __attribute__((ext_vector_type(4))) float f32x4;    // 4 fp32 acc

typedef __attribute__((address_space(1))) const uint32_t g_u32;
typedef __attribute__((address_space(3))) uint32_t l_u32;

static __device__ __forceinline__ uint16_t f2bf(float f) {
  union { float f; uint32_t u; } v; v.f = f;
  uint32_t r = (v.u + 0x7FFFu + ((v.u >> 16) & 1u)) >> 16;  // RNE
  return (uint16_t)r;
}

static __device__ __forceinline__ float bf2f(uint16_t u) {
  union { uint32_t u; float f; } v; v.u = ((uint32_t)u) << 16;
  return v.f;
}

static __device__ __forceinline__ float waveReduceSum(float x) {
#pragma unroll
  for (int m = 32; m > 0; m >>= 1) x += __shfl_xor(x, m, 64);
  return x;
}

// ---------------- zero the atomically-accumulated arrays (replaces memset)
__global__ __launch_bounds__(256) void k_zero(float* __restrict__ p, int n4) {
  const int i = blockIdx.x * 256 + threadIdx.x;
  if (i < n4) reinterpret_cast<float4*>(p)[i] = float4{0.f, 0.f, 0.f, 0.f};
}

// ---------------- N pass: b_i = ||n_i||^2, sn_l = sum_i N[i][l], Nt = bf16 N^T
// pre-swizzled per 32-k tile so a LINEAR 16KB gll copy yields swizzled LDS:
//   tile byte(l, k') = l*64 + ((k'>>3) ^ (l&3))*16 + (k'&7)*2,  k' in [0,32)
__global__ __launch_bounds__(256) void k_nt(const float* __restrict__ N,
                                            uint16_t* __restrict__ Nt,
                                            float* __restrict__ b,
                                            float* __restrict__ sn) {
  __shared__ __align__(16) uint16_t T[256 * 72];  // [l][k] k=0..63, pad 72
  const int i0 = blockIdx.x * 64;
  const int tid = threadIdx.x;
  const int wave = tid >> 6, lane = tid & 63;
  float sq[16];
  float snacc0 = 0.f, snacc1 = 0.f, snacc2 = 0.f, snacc3 = 0.f;
#pragma unroll
  for (int it = 0; it < 16; ++it) {
    const int k = wave + it * 4;
    const int l4 = lane * 4;
    const float4 v = *reinterpret_cast<const float4*>(N + (size_t)(i0 + k) * 256 + l4);
    T[(l4 + 0) * 72 + k] = f2bf(v.x);
    T[(l4 + 1) * 72 + k] = f2bf(v.y);
    T[(l4 + 2) * 72 + k] = f2bf(v.z);
    T[(l4 + 3) * 72 + k] = f2bf(v.w);
    sq[it] = v.x * v.x + v.y * v.y + v.z * v.z + v.w * v.w;
    snacc0 += v.x; snacc1 += v.y; snacc2 += v.z; snacc3 += v.w;
  }
  // batched butterfly reduce of the 16 row-square-sums across 64 lanes
#pragma unroll
  for (int m = 1; m < 64; m <<= 1) {
#pragma unroll
    for (int it = 0; it < 16; ++it) sq[it] += __shfl_xor(sq[it], m, 64);
  }
  float myv = sq[0];
#pragma unroll
  for (int it = 1; it < 16; ++it) myv = (lane == it) ? sq[it] : myv;
  if (lane < 16) b[i0 + wave + lane * 4] = myv;  // row = i0 + wave + it*4
  {
    const int l4 = lane * 4;
    atomicAdd(&sn[l4 + 0], snacc0); atomicAdd(&sn[l4 + 1], snacc1);
    atomicAdd(&sn[l4 + 2], snacc2); atomicAdd(&sn[l4 + 3], snacc3);
  }
  __syncthreads();
  const int l = tid;
#pragma unroll
  for (int tt = 0; tt < 2; ++tt) {
    const int tg = blockIdx.x * 2 + tt;  // global kstep (32-row tile) index
#pragma unroll
    for (int c = 0; c < 4; ++c) {
      const short8 v = *reinterpret_cast<const short8*>(&T[l * 72 + tt * 32 + c * 8]);
      *reinterpret_cast<short8*>((char*)Nt + (size_t)tg * 16384 + l * 64 +
                                 ((c ^ (l & 3)) << 4)) = v;
    }
  }
}

// ---------------- h1_i = sum_l N[i][l] * sn[l]  (one wave per row)
__global__ __launch_bounds__(256) void k_h1(const float* __restrict__ N,
                                            const float* __restrict__ sn,
                                            float* __restrict__ h1) {
  const int wave = threadIdx.x >> 6, lane = threadIdx.x & 63;
  const int i = blockIdx.x * 4 + wave;
  const float4 v = *reinterpret_cast<const float4*>(N + (size_t)i * 256 + lane * 4);
  const float4 s = *reinterpret_cast<const float4*>(sn + lane * 4);
  float d = v.x * s.x + v.y * s.y + v.z * s.z + v.w * s.w;
  d = waveReduceSum(d);
  if (lane == 0) h1[i] = d;
}

// ---------------- K-split GEMM + fused X statistics (the ONLY full X read).
// Per k-chunk kc: M_kc[l][p] = sum_{i in chunk} N[i][l] X[i][p]  (bf16 slices).
// Fused per-thread stats over the staged fp32 X values:
//   s1 += x^2, sb += b_i x^2, sh += h1_i x^2  (-> Sa, Sab, T1 scalars)
//   sxa += x, cxa += b_i x                    (-> sx[col], cx[col])
__global__ __launch_bounds__(256, 3) void k_gemm_f3(const float* __restrict__ X,
                                                    const uint16_t* __restrict__ Nt,
                                                    uint16_t* __restrict__ Mb,
                                                    const float* __restrict__ bvec,
                                                    const float* __restrict__ h1v,
                                                    float* __restrict__ sx,
                                                    float* __restrict__ cx,
                                                    float* __restrict__ scal,
                                                    int B, int D1) {
  __shared__ __align__(16) uint16_t NB[2][8192];   // 2 x 16 KB (256l x 32k bf16 swz)
  __shared__ __align__(16) uint16_t AB[2][64 * 40];
  __shared__ float SR[3][4];
  const int tid = threadIdx.x;
  const int w = tid >> 6, lane = tid & 63;
  const int lr = lane & 15, lh = lane >> 4;
  const int nks = B >> 7;                 // ksteps per chunk (32)
  const int pt = blockIdx.x >> 2, kc = blockIdx.x & 3;
  const int pbase = pt << 6;
  const int ks0 = kc * nks;               // starting global kstep

  f32x4 acc[4][4];
#pragma unroll
  for (int i = 0; i < 4; ++i)
#pragma unroll
    for (int j = 0; j < 4; ++j) acc[i][j] = (f32x4){0.f, 0.f, 0.f, 0.f};

  // A staging: thread owns col p = tid&63, k-octet ak8 = (tid>>6)*8 per 32-row step
  const int ap = tid & 63, ak8 = (tid >> 6) << 3;
  const float* Xbase = X + (size_t)(ks0 * 32 + ak8) * D1 + pbase + ap;
  float xr[8];
  float4 bv0, bv1, hv0, hv1;
  float s1 = 0.f, sb = 0.f, sh = 0.f, sxa = 0.f, cxa = 0.f;

#define GLL_B(S, BUF)                                                              \
  {                                                                                \
    const char* gsrc_ = (const char*)Nt + (size_t)(ks0 + (S)) * 16384 +            \
                        ((size_t)w << 10) + (size_t)lane * 16;                     \
    _Pragma("unroll")                                                              \
    for (int j_ = 0; j_ < 4; ++j_) {                                               \
      __builtin_amdgcn_global_load_lds((g_u32*)(gsrc_ + ((size_t)j_ << 12)),       \
                                       (l_u32*)&NB[BUF][(j_ * 4 + w) << 9],        \
                                       16, 0, 0);                                  \
    }                                                                              \
  }
#define A_LOADS(S)                                                                 \
  {                                                                                \
    const float* p_ = Xbase + (size_t)(S) * 32 * D1;                               \
    _Pragma("unroll")                                                              \
    for (int r_ = 0; r_ < 8; ++r_) xr[r_] = p_[(size_t)r_ * D1];                   \
    const int ib_ = ks0 * 32 + (S) * 32 + ak8;                                     \
    bv0 = *reinterpret_cast<const float4*>(bvec + ib_);                            \
    bv1 = *reinterpret_cast<const float4*>(bvec + ib_ + 4);                        \
    hv0 = *reinterpret_cast<const float4*>(h1v + ib_);                             \
    hv1 = *reinterpret_cast<const float4*>(h1v + ib_ + 4);                         \
  }

  GLL_B(0, 0);
  A_LOADS(0);

  for (int s = 0; s < nks; ++s) {
    const int buf = s & 1;
    {  // store A + fused stats (xr/bv/hv consumed here; vmcnt drain covers gll)
      union { uint16_t u[8]; short8 v; } pk;
      const float bb[8] = {bv0.x, bv0.y, bv0.z, bv0.w, bv1.x, bv1.y, bv1.z, bv1.w};
      const float hh[8] = {hv0.x, hv0.y, hv0.z, hv0.w, hv1.x, hv1.y, hv1.z, hv1.w};
#pragma unroll
      for (int r = 0; r < 8; ++r) {
        const float x = xr[r];
        pk.u[r] = f2bf(x);
        const float x2 = x * x;
        s1 += x2;
        sb += bb[r] * x2;
        sh += hh[r] * x2;
        sxa += x;
        cxa += bb[r] * x;
      }
      *reinterpret_cast<short8*>(&AB[buf][ap * 40 + ak8]) = pk.v;
    }
    __syncthreads();
    if (s + 1 < nks) {  // prefetch overlaps frag reads + MFMA below
      GLL_B(s + 1, buf ^ 1);
      A_LOADS(s + 1);
    }
    short8 af[4], bfv[4];
#pragma unroll
    for (int ps = 0; ps < 4; ++ps)
      af[ps] = *reinterpret_cast<const short8*>(&AB[buf][(ps * 16 + lr) * 40 + lh * 8]);
#pragma unroll
    for (int q = 0; q < 4; ++q) {
      const int l = (w << 6) + (q << 4) + lr;
      bfv[q] = *reinterpret_cast<const short8*>(&NB[buf][l * 32 + ((lh ^ (l & 3)) << 3)]);
    }
#pragma unroll
    for (int ps = 0; ps < 4; ++ps)
#pragma unroll
      for (int q = 0; q < 4; ++q)
        acc[ps][q] = __builtin_amdgcn_mfma_f32_16x16x32_bf16(af[ps], bfv[q], acc[ps][q], 0, 0, 0);
    __syncthreads();
  }
#undef GLL_B
#undef A_LOADS

  // M slice store, layout [l][p], bf16, plain stores (no init needed).
  // C/D layout: col(l)=lane&15 within q-tile, row(p)=(lane>>4)*4+e  [m89-verified]
  uint16_t* Mk = Mb + (size_t)kc * ((size_t)D1 * 256);
#pragma unroll
  for (int ps = 0; ps < 4; ++ps)
#pragma unroll
    for (int q = 0; q < 4; ++q) {
      const int l = (w << 6) + (q << 4) + lr;
      const int p0 = pbase + ps * 16 + lh * 4;
      ushort4 st;
      st.x = f2bf(acc[ps][q][0]); st.y = f2bf(acc[ps][q][1]);
      st.z = f2bf(acc[ps][q][2]); st.w = f2bf(acc[ps][q][3]);
      *reinterpret_cast<ushort4*>(&Mk[(size_t)l * D1 + p0]) = st;
    }

  // column stats
  atomicAdd(&sx[pbase + ap], sxa);
  atomicAdd(&cx[pbase + ap], cxa);

  // scalar stats: wave reduce -> LDS -> one atomic each per block
  s1 = waveReduceSum(s1); sb = waveReduceSum(sb); sh = waveReduceSum(sh);
  if (lane == 0) { SR[0][w] = s1; SR[1][w] = sb; SR[2][w] = sh; }
  __syncthreads();
  if (tid == 0) {
    atomicAdd(&scal[0], SR[0][0] + SR[0][1] + SR[0][2] + SR[0][3]);
    atomicAdd(&scal[1], SR[1][0] + SR[1][1] + SR[1][2] + SR[1][3]);
    atomicAdd(&scal[2], SR[2][0] + SR[2][1] + SR[2][2] + SR[2][3]);
  }
}

// ---------------- F = sum over elements of (m0+m1+m2+m3)^2, bf16 slices
__global__ __launch_bounds__(256) void k_square(const uint16_t* __restrict__ Mb,
                                                float* __restrict__ Fp,
                                                int n8, int slice) {
  __shared__ float red[4];
  float s = 0.f;
  for (int idx = blockIdx.x * 256 + threadIdx.x; idx < n8; idx += gridDim.x * 256) {
    union { short8 v; uint16_t u[8]; } m0, m1, m2, m3;
    m0.v = *reinterpret_cast<const short8*>(Mb + (size_t)idx * 8);
    m1.v = *reinterpret_cast<const short8*>(Mb + (size_t)idx * 8 + (size_t)slice);
    m2.v = *reinterpret_cast<const short8*>(Mb + (size_t)idx * 8 + 2 * (size_t)slice);
    m3.v = *reinterpret_cast<const short8*>(Mb + (size_t)idx * 8 + 3 * (size_t)slice);
#pragma unroll
    for (int e = 0; e < 8; ++e) {
      const float v = bf2f(m0.u[e]) + bf2f(m1.u[e]) + bf2f(m2.u[e]) + bf2f(m3.u[e]);
      s += v * v;
    }
  }
  s = waveReduceSum(s);
  const int wave = threadIdx.x >> 6, lane = threadIdx.x & 63;
  if (lane == 0) red[wave] = s;
  __syncthreads();
  if (threadIdx.x == 0) atomicAdd(Fp, red[0] + red[1] + red[2] + red[3]);
}

// ---------------- final combine
__global__ __launch_bounds__(256) void k_final3(const float* __restrict__ scal,
                                                const float* __restrict__ b,
                                                const float* __restrict__ sx,
                                                const float* __restrict__ cx,
                                                float* __restrict__ out,
                                                int B, int D1) {
  const int tid = threadIdx.x;
  float sb_ = 0.f, t2_ = 0.f;
  for (int i = tid; i < B; i += 256) sb_ += b[i];
  for (int k = tid; k < D1; k += 256) t2_ += sx[k] * cx[k];
  sb_ = waveReduceSum(sb_); t2_ = waveReduceSum(t2_);
  __shared__ float R[2][4];
  const int wave = tid >> 6, lane = tid & 63;
  if (lane == 0) { R[0][wave] = sb_; R[1][wave] = t2_; }
  __syncthreads();
  if (tid == 0) {
    double Sb = 0, T2 = 0;
    for (int w = 0; w < 4; ++w) { Sb += R[0][w]; T2 += R[1][w]; }
    const double Sa = scal[0], Sab = scal[1], T1 = scal[2], F = scal[3];
    const double total = 2.0 * (double)B * Sab + 2.0 * Sa * Sb - 4.0 * T1 - 4.0 * T2 + 4.0 * F;
    const double denom = (double)D1 * 256.0 * (double)B * (double)B;
    out[0] = (float)exp(-total / denom);
  }
}

// ================= fallback kernels (small workspace; round-1 verified path) ====
__global__ __launch_bounds__(256) void k_noise_b(const float* __restrict__ N,
                                                 float* __restrict__ b) {
  const int wave = threadIdx.x >> 6, lane = threadIdx.x & 63;
  const int i = blockIdx.x * 4 + wave;
  const float4 v = *reinterpret_cast<const float4*>(N + (size_t)i * 256 + lane * 4);
  float s = v.x * v.x + v.y * v.y + v.z * v.z + v.w * v.w;
  s = waveReduceSum(s);
  if (lane == 0) b[i] = s;
}

__global__ __launch_bounds__(256) void k_x_pass(const float* __restrict__ X,
                                                const float* __restrict__ b,
                                                float* __restrict__ a,
                                                float* __restrict__ sx,
                                                float* __restrict__ cx, int D1) {
  const int ncb = D1 >> 10;
  const int colblk = blockIdx.x % ncb;
  const int rowblk = blockIdx.x / ncb;
  const int wv = threadIdx.x >> 6, lane = threadIdx.x & 63;
  const int col = (colblk << 10) + (wv << 8) + (lane << 2);
  const int row0 = rowblk << 6;
  float s0 = 0.f, s1 = 0.f, s2 = 0.f, s3 = 0.f;
  float c0 = 0.f, c1 = 0.f, c2 = 0.f, c3 = 0.f;
  const float* p = X + (size_t)row0 * D1 + col;
  for (int r8 = 0; r8 < 64; r8 += 8) {
    float asq[8];
#pragma unroll
    for (int r = 0; r < 8; ++r) {
      const float4 v = *reinterpret_cast<const float4*>(p + (size_t)(r8 + r) * D1);
      const float bi = b[row0 + r8 + r];
      s0 += v.x; s1 += v.y; s2 += v.z; s3 += v.w;
      c0 += bi * v.x; c1 += bi * v.y; c2 += bi * v.z; c3 += bi * v.w;
      asq[r] = v.x * v.x + v.y * v.y + v.z * v.z + v.w * v.w;
    }
#pragma unroll
    for (int m = 1; m < 64; m <<= 1) {
#pragma unroll
      for (int r = 0; r < 8; ++r) asq[r] += __shfl_xor(asq[r], m, 64);
    }
    float myv = asq[0];
#pragma unroll
    for (int r = 1; r < 8; ++r) myv = (lane == r) ? asq[r] : myv;
    if (lane < 8) atomicAdd(&a[row0 + r8 + lane], myv);
  }
  atomicAdd(&sx[col + 0], s0); atomicAdd(&sx[col + 1], s1);
  atomicAdd(&sx[col + 2], s2); atomicAdd(&sx[col + 3], s3);
  atomicAdd(&cx[col + 0], c0); atomicAdd(&cx[col + 1], c1);
  atomicAdd(&cx[col + 2], c2); atomicAdd(&cx[col + 3], c3);
}

__global__ __launch_bounds__(256) void k_noise2(const float* __restrict__ N,
                                                const float* __restrict__ a,
                                                float* __restrict__ sn,
                                                float* __restrict__ an) {
  const int t = threadIdx.x;
  const int i0 = blockIdx.x << 6;
  float ssn = 0.f, san = 0.f;
  for (int r = 0; r < 64; ++r) {
    const int i = i0 + r;
    const float v = N[(size_t)i * 256 + t];
    ssn += v;
    san += a[i] * v;
  }
  atomicAdd(&sn[t], ssn);
  atomicAdd(&an[t], san);
}

__global__ __launch_bounds__(256) void k_gemm_f(const float* __restrict__ X,
                                                const float* __restrict__ Nz,
                                                float* __restrict__ Fout,
                                                int B, int D1) {
  __shared__ uint16_t Abf[64 * 40];
  __shared__ uint16_t Bbf[256 * 40];
  __shared__ float red[4];
  const int tid = threadIdx.x;
  const int pbase = blockIdx.x << 6;
  const int wave = tid >> 6, lane = tid & 63;
  const int lr = lane & 15, lh = lane >> 4;

  f32x4 acc[4][4];
#pragma unroll
  for (int i = 0; i < 4; ++i)
#pragma unroll
    for (int j = 0; j < 4; ++j) acc[i][j] = (f32x4){0.f, 0.f, 0.f, 0.f};

  const int igx = tid & 7, p4x = ((tid >> 3) & 15) << 2;
  const int ign0 = tid & 7, l4n0 = (tid >> 3) << 2;
  const int ign1 = (tid + 256) & 7, l4n1 = ((tid + 256) >> 3) << 2;

  float4 xr0, xr1, xr2, xr3;
  float4 n0r0, n0r1, n0r2, n0r3;
  float4 n1r0, n1r1, n1r2, n1r3;

  auto load_stage = [&](int i0) {
    if (tid < 128) {
      const float* src = X + (size_t)(i0 + igx * 4) * D1 + pbase + p4x;
      xr0 = *reinterpret_cast<const float4*>(src);
      xr1 = *reinterpret_cast<const float4*>(src + D1);
      xr2 = *reinterpret_cast<const float4*>(src + 2 * (size_t)D1);
      xr3 = *reinterpret_cast<const float4*>(src + 3 * (size_t)D1);
    }
    {
      const float* src = Nz + (size_t)(i0 + ign0 * 4) * 256 + l4n0;
      n0r0 = *reinterpret_cast<const float4*>(src);
      n0r1 = *reinterpret_cast<const float4*>(src + 256);
      n0r2 = *reinterpret_cast<const float4*>(src + 512);
      n0r3 = *reinterpret_cast<const float4*>(src + 768);
    }
    {
      const float* src = Nz + (size_t)(i0 + ign1 * 4) * 256 + l4n1;
      n1r0 = *reinterpret_cast<const float4*>(src);
      n1r1 = *reinterpret_cast<const float4*>(src + 256);
      n1r2 = *reinterpret_cast<const float4*>(src + 512);
      n1r3 = *reinterpret_cast<const float4*>(src + 768);
    }
  };

  auto store_stage = [&]() {
    ushort4 w;
    if (tid < 128) {
      w.x = f2bf(xr0.x); w.y = f2bf(xr1.x); w.z = f2bf(xr2.x); w.w = f2bf(xr3.x);
      *reinterpret_cast<ushort4*>(&Abf[(p4x + 0) * 40 + igx * 4]) = w;
      w.x = f2bf(xr0.y); w.y = f2bf(xr1.y); w.z = f2bf(xr2.y); w.w = f2bf(xr3.y);
      *reinterpret_cast<ushort4*>(&Abf[(p4x + 1) * 40 + igx * 4]) = w;
      w.x = f2bf(xr0.z); w.y = f2bf(xr1.z); w.z = f2bf(xr2.z); w.w = f2bf(xr3.z);
      *reinterpret_cast<ushort4*>(&Abf[(p4x + 2) * 40 + igx * 4]) = w;
      w.x = f2bf(xr0.w); w.y = f2bf(xr1.w); w.z = f2bf(xr2.w); w.w = f2bf(xr3.w);
      *reinterpret_cast<ushort4*>(&Abf[(p4x + 3) * 40 + igx * 4]) = w;
    }
    w.x = f2bf(n0r0.x); w.y = f2bf(n0r1.x); w.z = f2bf(n0r2.x); w.w = f2bf(n0r3.x);
    *reinterpret_cast<ushort4*>(&Bbf[(l4n0 + 0) * 40 + ign0 * 4]) = w;
    w.x = f2bf(n0r0.y); w.y = f2bf(n0r1.y); w.z = f2bf(n0r2.y); w.w = f2bf(n0r3.y);
    *reinterpret_cast<ushort4*>(&Bbf[(l4n0 + 1) * 40 + ign0 * 4]) = w;
    w.x = f2bf(n0r0.z); w.y = f2bf(n0r1.z); w.z = f2bf(n0r2.z); w.w = f2bf(n0r3.z);
    *reinterpret_cast<ushort4*>(&Bbf[(l4n0 + 2) * 40 + ign0 * 4]) = w;
    w.x = f2bf(n0r0.w); w.y = f2bf(n0r1.w); w.z = f2bf(n0r2.w); w.w = f2bf(n0r3.w);
    *reinterpret_cast<ushort4*>(&Bbf[(l4n0 + 3) * 40 + ign0 * 4]) = w;

    w.x = f2bf(n1r0.x); w.y = f2bf(n1r1.x); w.z = f2bf(n1r2.x); w.w = f2bf(n1r3.x);
    *reinterpret_cast<ushort4*>(&Bbf[(l4n1 + 0) * 40 + ign1 * 4]) = w;
    w.x = f2bf(n1r0.y); w.y = f2bf(n1r1.y); w.z = f2bf(n1r2.y); w.w = f2bf(n1r3.y);
    *reinterpret_cast<ushort4*>(&Bbf[(l4n1 + 1) * 40 + ign1 * 4]) = w;
    w.x = f2bf(n1r0.z); w.y = f2bf(n1r1.z); w.z = f2bf(n1r2.z); w.w = f2bf(n1r3.z);
    *reinterpret_cast<ushort4*>(&Bbf[(l4n1 + 2) * 40 + ign1 * 4]) = w;
    w.x = f2bf(n1r0.w); w.y = f2bf(n1r1.w); w.z = f2bf(n1r2.w); w.w = f2bf(n1r3.w);
    *reinterpret_cast<ushort4*>(&Bbf[(l4n1 + 3) * 40 + ign1 * 4]) = w;
  };

  load_stage(0);
  for (int i0 = 0; i0 < B; i0 += 32) {
    store_stage();
    __syncthreads();
    if (i0 + 32 < B) load_stage(i0 + 32);

    short8 af[4], bfv[4];
#pragma unroll
    for (int ps = 0; ps < 4; ++ps)
      af[ps] = *reinterpret_cast<const short8*>(&Abf[(ps * 16 + lr) * 40 + lh * 8]);
#pragma unroll
    for (int q = 0; q < 4; ++q)
      bfv[q] = *reinterpret_cast<const short8*>(&Bbf[((wave * 4 + q) * 16 + lr) * 40 + lh * 8]);
#pragma unroll
    for (int ps = 0; ps < 4; ++ps)
#pragma unroll
      for (int q = 0; q < 4; ++q)
        acc[ps][q] = __builtin_amdgcn_mfma_f32_16x16x32_bf16(af[ps], bfv[q], acc[ps][q], 0, 0, 0);
    __syncthreads();
  }

  float loc = 0.f;
#pragma unroll
  for (int ps = 0; ps < 4; ++ps)
#pragma unroll
    for (int q = 0; q < 4; ++q)
#pragma unroll
      for (int e = 0; e < 4; ++e) loc += acc[ps][q][e] * acc[ps][q][e];
  loc = waveReduceSum(loc);
  if (lane == 0) red[wave] = loc;
  __syncthreads();
  if (tid == 0) atomicAdd(Fout, red[0] + red[1] + red[2] + red[3]);
}

__global__ __launch_bounds__(256) void k_final(const float* __restrict__ a,
                                               const float* __restrict__ b,
                                               const float* __restrict__ sx,
                                               const float* __restrict__ cx,
                                               const float* __restrict__ sn,
                                               const float* __restrict__ an,
                                               const float* __restrict__ Fp,
                                               float* __restrict__ out, int B, int D1) {
  const int tid = threadIdx.x;
  float sa = 0.f, sb = 0.f, sab = 0.f, t2 = 0.f;
  for (int i = tid; i < B; i += 256) {
    const float ai = a[i], bi = b[i];
    sa += ai; sb += bi; sab += ai * bi;
  }
  float t1 = an[tid] * sn[tid];
  for (int k = tid; k < D1; k += 256) t2 += cx[k] * sx[k];

  sa = waveReduceSum(sa); sb = waveReduceSum(sb); sab = waveReduceSum(sab);
  t1 = waveReduceSum(t1); t2 = waveReduceSum(t2);
  __shared__ float R[5][4];
  const int wave = tid >> 6, lane = tid & 63;
  if (lane == 0) { R[0][wave] = sa; R[1][wave] = sb; R[2][wave] = sab; R[3][wave] = t1; R[4][wave] = t2; }
  __syncthreads();
  if (tid == 0) {
    double Sa = 0, Sb = 0, Sab = 0, T1 = 0, T2 = 0;
    for (int w = 0; w < 4; ++w) {
      Sa += R[0][w]; Sb += R[1][w]; Sab += R[2][w]; T1 += R[3][w]; T2 += R[4][w];
    }
    const double F = (double)Fp[0];
    const double total = 2.0 * (double)B * Sab + 2.0 * Sa * Sb - 4.0 * T1 - 4.0 * T2 + 4.0 * F;
    const double denom = (double)D1 * 256.0 * (double)B * (double)B;
    out[0] = (float)exp(-total / denom);
  }
}

extern "C" void kernel_launch(void* const* d_in, const int* in_sizes, int n_in,
                              void* d_out, int out_size, void* d_ws, size_t ws_size,
                              hipStream_t stream) {
  const float* noises = (const float*)d_in[0];   // [B, 256]
  const float* images = (const float*)d_in[1];   // [B, D1]
  const int B = in_sizes[0] / 256;               // 4096
  const int D1 = in_sizes[1] / B;                // 12288
  float* outf = (float*)d_out;
  float* ws = (float*)d_ws;

  // ---- main path layout (floats) ----
  // [0, D1)            sx         (atomic, zeroed)
  // [D1, 2*D1)         cx         (atomic, zeroed)
  // [2*D1, 2*D1+256)   sn         (atomic, zeroed)
  // [2*D1+256, +16)    scal: {Sa, Sab, T1, F} (atomic, zeroed)
  // [2*D1+272, +B)     b          (written fully)
  // [.. +B)            h1         (written fully)
  // then Nt (B*256 bf16, written fully), then Mb (4 * D1*256 bf16, written fully)
  float* sx   = ws;
  float* cx   = ws + D1;
  float* sn   = ws + 2 * D1;
  float* scal = ws + 2 * D1 + 256;
  float* b    = ws + 2 * D1 + 272;
  float* h1   = b + B;
  const size_t nt_off_f = (size_t)2 * D1 + 272 + 2 * (size_t)B;      // floats
  const size_t nt_off_a = (nt_off_f + 3) & ~(size_t)3;               // 16B align
  uint16_t* Nt = (uint16_t*)(ws + nt_off_a);                         // B*256 u16
  const size_t mb_off_f = nt_off_a + ((size_t)B * 256) / 2;
  uint16_t* Mb = (uint16_t*)(ws + mb_off_f);                         // 4*D1*256 u16
  const size_t need = (mb_off_f + 2 * (size_t)D1 * 256) * sizeof(float);

  if (ws_size >= need) {
    const int nzero4 = (2 * D1 + 272) / 4;       // sx, cx, sn, scal
    k_zero<<<(nzero4 + 255) / 256, 256, 0, stream>>>(ws, nzero4);
    k_nt<<<B / 64, 256, 0, stream>>>(noises, Nt, b, sn);
    k_h1<<<B / 4, 256, 0, stream>>>(noises, sn, h1);
    k_gemm_f3<<<(D1 / 64) * 4, 256, 0, stream>>>(images, Nt, Mb, b, h1, sx, cx, scal, B, D1);
    k_square<<<512, 256, 0, stream>>>(Mb, &scal[3], D1 * 256 / 8, D1 * 256);
    k_final3<<<1, 256, 0, stream>>>(scal, b, sx, cx, outf, B, D1);
  } else {
    // round-1 verified fallback (small workspace)
    float* a2  = ws;                         // B
    float* b2  = ws + B;                     // B
    float* sx2 = ws + 2 * B;                 // D1
    float* cx2 = ws + 2 * B + D1;            // D1
    float* sn2 = ws + 2 * B + 2 * D1;        // 256
    float* an2 = ws + 2 * B + 2 * D1 + 256;  // 256
    float* Fp2 = ws + 2 * B + 2 * D1 + 512;  // 1
    const int nzero4 = (2 * B + 2 * D1 + 516) / 4;
    k_zero<<<(nzero4 + 255) / 256, 256, 0, stream>>>(ws, nzero4);
    k_noise_b<<<B / 4, 256, 0, stream>>>(noises, b2);
    k_x_pass<<<(D1 / 1024) * (B / 64), 256, 0, stream>>>(images, b2, a2, sx2, cx2, D1);
    k_noise2<<<B / 64, 256, 0, stream>>>(noises, a2, sn2, an2);
    k_gemm_f<<<D1 / 64, 256, 0, stream>>>(images, noises, Fp2, B, D1);
    k_final<<<1, 256, 0, stream>>>(a2, b2, sx2, cx2, sn2, an2, Fp2, outf, B, D1);
  }
}